// Round 10
// baseline (1522.505 us; speedup 1.0000x reference)
//
#include <hip/hip_runtime.h>
#include <hip/hip_bf16.h>
#include <math.h>

#define B_   4096
#define T_   16
#define F_   256
#define U_   512
#define M_   8
#define K_   768    // F+U
#define NRS  4096   // U*M
#define NC   8192   // combined R|S output cols
#define LNT  1.1512925f  // 0.5*ln(10)

// chunk-major pre-tiled panel constants
#define XPH  32768   // x panel per (t,mh): 8 kt * 4096
#define XPT  1048576 // x per t: 32 mh * XPH
#define HPH  65536   // h panel per mh: 16 kt * 4096
#define BPH  98304   // B panel per NH: 24 kt * 4096
#define QPP  12288   // Bq16 panel per nh: 24 kt * 512

typedef __bf16 bf16_t;
typedef bf16_t bf16x8 __attribute__((ext_vector_type(8)));
typedef bf16_t bf16x4 __attribute__((ext_vector_type(4)));
typedef float  f32x4  __attribute__((ext_vector_type(4)));

__device__ inline void gl_lds16(const void* g, void* lds) {
    __builtin_amdgcn_global_load_lds(
        (const __attribute__((address_space(1))) unsigned int*)g,
        (__attribute__((address_space(3))) unsigned int*)lds, 16, 0, 0);
}

#define VMCNT(n) asm volatile("s_waitcnt vmcnt(" #n ")" ::: "memory")
#define LGKM0()  asm volatile("s_waitcnt lgkmcnt(0)" ::: "memory")
#define BAR()    __builtin_amdgcn_s_barrier()

// Chunk-major BK=32 slot: [4 ch][128 rows][8 bf16] = 8 KB; chunk c holds
// k=c*8..+7. Staging = 2 linear 16B loads/thread (256 thr). Reads: 16-lane
// quarter (fixed chunk) reads 16 consecutive rows x 16B -> 2-way free.
__device__ inline void stage8(const bf16_t* src, bf16_t* dst, int tid) {
    gl_lds16(src + tid * 8,        (char*)dst + tid * 16);
    gl_lds16(src + tid * 8 + 2048, (char*)dst + tid * 16 + 4096);
}

// ---------------------------------------------------------------------------
// R-half GEMM (verbatim R7/R9): 128x128 tile, 4 waves (2Mx2N), BK=32,
// 24 tiles, single-barrier parity schedule, 32 KiB LDS, 4 blk/CU.
// Epilogue: softmax + r*hhat reduce -> rh.
// ---------------------------------------------------------------------------
__global__ __launch_bounds__(256, 4) void gemm_r(
    const bf16_t* __restrict__ xt_t,   // [32 mh][8 kt][4][128][8]
    const bf16_t* __restrict__ ht,     // [32 mh][16 kt][4][128][8] (h(t-1))
    const bf16_t* __restrict__ Bt,     // [64 NH][24 kt][4][128][8]
    const float*  __restrict__ biasP,  // [NC] (perm)
    const bf16_t* __restrict__ hhat,   // [B_][NRS]
    bf16_t* __restrict__ rh)           // [B_][U_]
{
    __shared__ __attribute__((aligned(16))) bf16_t Ahl[2][4096];
    __shared__ __attribute__((aligned(16))) bf16_t Bhl[2][4096];

    const int tid  = threadIdx.x;
    const int lane = tid & 63;
    const int wave = tid >> 6;

    const int lin = blockIdx.y * 32 + blockIdx.x;   // 1024 blocks
    const int c = lin & 7, q = lin >> 3;
    const int mh = (c >> 1) * 8 + (q & 7);
    const int nh = (c & 1) * 16 + (q >> 3);
    const int m0 = mh * 128;
    const int NH = nh;                              // R half

    const int wm = wave >> 1;
    const int wn = wave & 1;
    const int lr = lane & 15;
    const int kq = lane >> 4;

    const bf16_t* xp = xt_t + (size_t)mh * XPH;
    const bf16_t* hp = ht   + (size_t)mh * HPH;
    const bf16_t* bp = Bt   + (size_t)NH * BPH;

    const int aoff = kq * 1024 + (wm * 64 + lr) * 8;
    const int boff = kq * 1024 + (wn * 64 + lr) * 8;

    f32x4 acc[4][4] = {};

    stage8(xp, &Ahl[0][0], tid);
    stage8(bp, &Bhl[0][0], tid);
    VMCNT(0);
    BAR();

#pragma unroll
    for (int tt = 0; tt < 24; ++tt) {
        const int p = tt & 1, pn = p ^ 1;
        if (tt < 23) {
            const bf16_t* as = (tt + 1 < 8) ? xp + (tt + 1) * 4096
                                            : hp + (tt + 1 - 8) * 4096;
            stage8(as, &Ahl[pn][0], tid);
            stage8(bp + (tt + 1) * 4096, &Bhl[pn][0], tid);
        }
        bf16x8 a[4], b[4];
#pragma unroll
        for (int i = 0; i < 4; ++i)
            a[i] = *(const bf16x8*)(&Ahl[p][0] + aoff + i * 128);
#pragma unroll
        for (int j = 0; j < 4; ++j)
            b[j] = *(const bf16x8*)(&Bhl[p][0] + boff + j * 128);
        LGKM0();
        __builtin_amdgcn_s_setprio(1);
#pragma unroll
        for (int i = 0; i < 4; ++i)
#pragma unroll
            for (int j = 0; j < 4; ++j)
                acc[i][j] = __builtin_amdgcn_mfma_f32_16x16x32_bf16(
                    a[i], b[j], acc[i][j], 0, 0, 0);
        __builtin_amdgcn_s_setprio(0);
        VMCNT(0);
        BAR();
    }

    const int nb  = NH * 128 + wn * 64;
    const int u3  = lane & 7;
    const int m0v = ((lane >> 3) & 1) * 4;

    float bj4[4];
#pragma unroll
    for (int j = 0; j < 4; ++j) bj4[j] = biasP[nb + j * 16 + lr];

#pragma unroll
    for (int mi = 0; mi < 4; ++mi) {
        const int rowb = m0 + wm * 64 + mi * 16 + kq * 4;
#pragma unroll
        for (int r = 0; r < 4; ++r) {
            const int row = rowb + r;
            float e[4], sum = 0.f;
#pragma unroll
            for (int j = 0; j < 4; ++j) {
                float v = acc[mi][j][r] + bj4[j];
                float d = v - (float)(m0v + j) * LNT;
                e[j] = __expf(-d * d);
                sum += e[j];
            }
            sum += __shfl_xor(sum, 8, 64);
            const float inv = 1.0f / sum;
            bf16x4 h4 = *(const bf16x4*)(hhat + (size_t)row * NRS + nb + u3 * 8 + m0v);
            float rhv = 0.f;
#pragma unroll
            for (int j = 0; j < 4; ++j) rhv += e[j] * inv * (float)h4[j];
            rhv += __shfl_xor(rhv, 8, 64);
            if ((lane & 8) == 0)
                rh[(size_t)row * U_ + (nb >> 3) + u3] = (bf16_t)rhv;
        }
    }
}

// ---------------------------------------------------------------------------
// FUSED S-GEMM + q-GEMM + state update. Block = 128 rows x 128 S-cols
// (= 16 u), grid 1024, 4 waves, 40 KiB LDS -> 4 blk/CU.
// Phase 1 (REWORKED vs R9): q-GEMM fully FRAGMENT-DIRECT — no LDS, no
//   barriers. x-frags are coalesced 16B/lane from the chunk-major xtile;
//   rh-frags are 16B/lane from the L2-resident rh (1MB/XCD slice); Wq frag
//   is a 1KB coalesced tile. 24 unrolled iters x 2 MFMA, compiler-pipelined.
//   (R9's staged version spent ~30us on 24 vmcnt(0)+BAR tiles for 2 MFMA
//   each — the measured regression source.) tanh -> qls, one BAR.
// Phase 2: S K-loop — verbatim R7 schedule.
// Phase 3: softmax -> s in-register; hn=((1-s)h+s q)DEC in place; write
//   hhat, hall, htile(w). FIRST=1: h=rh=hhat=0 -> 8 tiles, no hhat read.
// ---------------------------------------------------------------------------
template <int FIRST>
__global__ __launch_bounds__(256, 4) void gemm_sq(
    const bf16_t* __restrict__ xt_t,   // [32 mh][8 kt][4][128][8]
    const bf16_t* __restrict__ htr,    // h(t-1) tiles (read)
    const bf16_t* __restrict__ Bt,     // [64 NH][24 kt][4][128][8]
    const float*  __restrict__ biasP,  // [NC] (perm)
    const bf16_t* __restrict__ rh,     // [B_][U_]
    const bf16_t* __restrict__ Bq16,   // [32 nh][24 kt][4][16][8]
    const float*  __restrict__ bq,     // [U_]
    bf16_t* __restrict__ hhat,         // [B_][NRS] read(t-1)+write(t)
    bf16_t* __restrict__ hnext,        // hall slice t+1: [B_][U_]
    bf16_t* __restrict__ htw)          // h(t) tiles (write)
{
    __shared__ __attribute__((aligned(16))) bf16_t Ahl[2][4096];  // 16 KB
    __shared__ __attribute__((aligned(16))) bf16_t Bhl[2][4096];  // 16 KB
    __shared__ __attribute__((aligned(16))) float  qls[2048];     // 8 KB q[128][16]

    const int tid  = threadIdx.x;
    const int lane = tid & 63;
    const int wave = tid >> 6;

    const int lin = blockIdx.y * 32 + blockIdx.x;   // 1024 blocks
    const int c = lin & 7, qq = lin >> 3;
    const int mh = (c >> 1) * 8 + (qq & 7);
    const int nh = (c & 1) * 16 + (qq >> 3);
    const int m0 = mh * 128;
    const int NH = 32 + nh;                         // S half

    const int wm = wave >> 1;
    const int wn = wave & 1;
    const int lr = lane & 15;
    const int kq = lane >> 4;

    const bf16_t* xp = xt_t + (size_t)mh * XPH;
    const bf16_t* hp = htr  + (size_t)mh * HPH;
    const bf16_t* bp = Bt   + (size_t)NH * BPH;
    const bf16_t* bqp = Bq16 + (size_t)nh * QPP;

    const int NT = FIRST ? 8 : 24;

    // ---------------- Phase 1: q GEMM, fragment-direct ---------------------
    {
        f32x4 accq[2] = {};
        const bf16_t* bqk = bqp + kq * 128 + lr * 8;
        const bf16_t* xf  = xp + kq * 1024 + (wave * 32 + lr) * 8;
#pragma unroll
        for (int kt = 0; kt < 8; ++kt) {
            bf16x8 bqf = *(const bf16x8*)(bqk + kt * 512);
            bf16x8 a0  = *(const bf16x8*)(xf + kt * 4096);
            bf16x8 a1  = *(const bf16x8*)(xf + kt * 4096 + 128);
            accq[0] = __builtin_amdgcn_mfma_f32_16x16x32_bf16(a0, bqf, accq[0], 0, 0, 0);
            accq[1] = __builtin_amdgcn_mfma_f32_16x16x32_bf16(a1, bqf, accq[1], 0, 0, 0);
        }
        if (!FIRST) {
            const bf16_t* rf0 = rh + (size_t)(m0 + wave * 32 + lr) * U_ + kq * 8;
            const bf16_t* rf1 = rf0 + (size_t)16 * U_;
#pragma unroll
            for (int kt = 0; kt < 16; ++kt) {
                bf16x8 bqf = *(const bf16x8*)(bqk + (8 + kt) * 512);
                bf16x8 a0  = *(const bf16x8*)(rf0 + kt * 32);
                bf16x8 a1  = *(const bf16x8*)(rf1 + kt * 32);
                accq[0] = __builtin_amdgcn_mfma_f32_16x16x32_bf16(a0, bqf, accq[0], 0, 0, 0);
                accq[1] = __builtin_amdgcn_mfma_f32_16x16x32_bf16(a1, bqf, accq[1], 0, 0, 0);
            }
        }
        const float bqv = bq[nh * 16 + lr];
#pragma unroll
        for (int i = 0; i < 2; ++i)
#pragma unroll
            for (int r = 0; r < 4; ++r)
                qls[(wave * 32 + i * 16 + kq * 4 + r) * 16 + lr] =
                    tanhf(accq[i][r] + bqv);
    }
    BAR();

    // ---------------- Phase 2: S GEMM (verbatim R7 schedule) ---------------
    const int aoff = kq * 1024 + (wm * 64 + lr) * 8;
    const int boff = kq * 1024 + (wn * 64 + lr) * 8;

    f32x4 acc[4][4] = {};

    stage8(xp, &Ahl[0][0], tid);
    stage8(bp, &Bhl[0][0], tid);
    VMCNT(0);
    BAR();

#pragma unroll
    for (int tt = 0; tt < NT; ++tt) {
        const int p = tt & 1, pn = p ^ 1;
        if (tt < NT - 1) {
            const bf16_t* as = (tt + 1 < 8) ? xp + (tt + 1) * 4096
                                            : hp + (tt + 1 - 8) * 4096;
            stage8(as, &Ahl[pn][0], tid);
            stage8(bp + (tt + 1) * 4096, &Bhl[pn][0], tid);
        }
        bf16x8 a[4], b[4];
#pragma unroll
        for (int i = 0; i < 4; ++i)
            a[i] = *(const bf16x8*)(&Ahl[p][0] + aoff + i * 128);
#pragma unroll
        for (int j = 0; j < 4; ++j)
            b[j] = *(const bf16x8*)(&Bhl[p][0] + boff + j * 128);
        LGKM0();
        __builtin_amdgcn_s_setprio(1);
#pragma unroll
        for (int i = 0; i < 4; ++i)
#pragma unroll
            for (int j = 0; j < 4; ++j)
                acc[i][j] = __builtin_amdgcn_mfma_f32_16x16x32_bf16(
                    a[i], b[j], acc[i][j], 0, 0, 0);
        __builtin_amdgcn_s_setprio(0);
        VMCNT(0);
        BAR();
    }

    // ---------------- Phase 3: softmax + state update ----------------------
    const int nb  = NH * 128 + wn * 64;          // perm col base (S range)
    const int u3  = lane & 7;
    const int m0v = ((lane >> 3) & 1) * 4;
    const int hcol = nh * 128 + wn * 64;         // hhat col base

    const float DECL[4] = {0.0f, 0.9658531f, 0.9827783f, 0.9884856f};
    const float DECH[4] = {0.9913518f, 0.9930754f, 0.9942261f, 0.9950489f};

    float bj4[4];
#pragma unroll
    for (int j = 0; j < 4; ++j) bj4[j] = biasP[nb + j * 16 + lr];

#pragma unroll
    for (int mi = 0; mi < 4; ++mi) {
        const int rowb = m0 + wm * 64 + mi * 16 + kq * 4;
        const int rlb  = wm * 64 + mi * 16 + kq * 4;
#pragma unroll
        for (int r = 0; r < 4; ++r) {
            const int row = rowb + r;
            float e[4], sum = 0.f;
#pragma unroll
            for (int j = 0; j < 4; ++j) {
                float v = acc[mi][j][r] + bj4[j];
                float d = v - (float)(m0v + j) * LNT;
                e[j] = __expf(-d * d);
                sum += e[j];
            }
            sum += __shfl_xor(sum, 8, 64);
            const float inv = 1.0f / sum;
            const float qv = qls[(rlb + r) * 16 + wn * 8 + u3];

            const size_t ha = (size_t)row * NRS + hcol + u3 * 8 + m0v;
            bf16x4 h4;
            if (!FIRST) h4 = *(const bf16x4*)(hhat + ha);
            bf16x4 ho;
            float hs = 0.f;
#pragma unroll
            for (int j = 0; j < 4; ++j) {
                float s = e[j] * inv;
                float h = FIRST ? 0.f : (float)h4[j];
                float dec = m0v ? DECH[j] : DECL[j];
                float hn = ((1.f - s) * h + s * qv) * dec;
                ho[j] = (bf16_t)hn;
                hs += hn;
            }
            *(bf16x4*)(hhat + ha) = ho;
            hs += __shfl_xor(hs, 8, 64);
            if ((lane & 8) == 0) {
                const int u = nh * 16 + wn * 8 + u3;
                hnext[(size_t)row * U_ + u] = (bf16_t)hs;
                htw[((size_t)(row >> 7) * 16 + (u >> 5)) * 4096
                    + ((((u >> 3) & 3) * 128) + (row & 127)) * 8 + (u & 7)] = (bf16_t)hs;
            }
        }
    }
}

// dst[p][K_] = bf16(src[K_][NRS] col L), rows permuted within 64-groups.
__global__ void transpose_perm(const float* __restrict__ src, bf16_t* __restrict__ dst) {
    __shared__ float tl[32][33];
    int k0 = blockIdx.x * 32, n0 = blockIdx.y * 32;
    int tx = threadIdx.x & 31, ty = threadIdx.x >> 5;
#pragma unroll
    for (int i = 0; i < 32; i += 8)
        tl[ty + i][tx] = src[(size_t)(k0 + ty + i) * NRS + n0 + tx];
    __syncthreads();
#pragma unroll
    for (int i = 0; i < 32; i += 8) {
        int n = n0 + ty + i;
        int m = n & 7, u3v = (n >> 3) & 7;
        int p = (n & ~63) + (m & 3) * 16 + (m >> 2) * 8 + u3v;
        dst[(size_t)p * K_ + k0 + tx] = (bf16_t)tl[tx][ty + i];
    }
}

// BtN[NH][kt][4][128][8] (chunk-major) from WrsT [NC][K_] (perm rows).
__global__ void btile_build(const bf16_t* __restrict__ WrsT, bf16_t* __restrict__ Bt) {
    int n = blockIdx.x / 3;
    int k = (blockIdx.x % 3) * 256 + threadIdx.x;
    int NH = n >> 7, prow = n & 127;
    int kt = k >> 5, ch = (k >> 3) & 3, e = k & 7;
    Bt[(size_t)NH * BPH + (((size_t)kt * 4 + ch) * 128 + prow) * 8 + e]
        = WrsT[(size_t)n * K_ + k];
}

// Bq16[nh][kt][4 ch][16][8] from W_q f32 [K_][U_] (coalesced src read).
__global__ void bq16_build(const float* __restrict__ Wq, bf16_t* __restrict__ Bq16) {
    int i = blockIdx.x * 256 + threadIdx.x;   // K_*U_
    int k = i >> 9, u = i & 511;
    int nh = u >> 4, ul = u & 15;
    int kt = k >> 5, ch = (k >> 3) & 3, e = k & 7;
    Bq16[(size_t)nh * QPP + ((size_t)kt * 4 + ch) * 128 + ul * 8 + e] = (bf16_t)Wq[i];
}

__global__ void bias_perm(const float* __restrict__ b_r, const float* __restrict__ b_s,
                          float* __restrict__ biasP) {
    int p = blockIdx.x * 256 + threadIdx.x;  // NC
    int pr = p & 63, j = pr >> 4, lr = pr & 15;
    int L = (p & ~63) + (lr & 7) * 8 + ((lr >> 3) & 1) * 4 + j;
    biasP[p] = (L < NRS) ? b_r[L] : b_s[L - NRS];
}

// xtN[t][mh][kt][4][128][8] (chunk-major) from x f32 [B][T][F]. Vectorized:
// one thread = one 8-f chunk (2x float4 in, 1x bf16x8 out).
__global__ void xtile_build(const float* __restrict__ x, bf16_t* __restrict__ xt) {
    int idx = blockIdx.x * 256 + threadIdx.x;  // B_*T_*F_/8
    int b = idx >> 9;
    int rem = idx & 511;
    int t = rem >> 5, c8 = rem & 31;
    int f0 = c8 * 8;
    const float* src = x + ((size_t)b * T_ + t) * F_ + f0;
    float4 v0 = *(const float4*)(src);
    float4 v1 = *(const float4*)(src + 4);
    bf16x8 o;
    o[0] = (bf16_t)v0.x; o[1] = (bf16_t)v0.y; o[2] = (bf16_t)v0.z; o[3] = (bf16_t)v0.w;
    o[4] = (bf16_t)v1.x; o[5] = (bf16_t)v1.y; o[6] = (bf16_t)v1.z; o[7] = (bf16_t)v1.w;
    int mh = b >> 7, prow = b & 127;
    int kt = f0 >> 5, ch = (f0 >> 3) & 3;
    *(bf16x8*)(xt + (size_t)t * XPT + (size_t)mh * XPH
               + (((size_t)kt * 4 + ch) * 128 + prow) * 8) = o;
}

// One launch for all T steps: out[b,t,:] = hall[t][b][:] @ Wout + bout.
__global__ __launch_bounds__(256) void out_all(
    const bf16_t* __restrict__ hall,   // [T_][B_][U_] (slices 1..16 of alloc)
    const float* __restrict__ Wout,
    const float* __restrict__ bout,
    float* __restrict__ out)
{
    int row = blockIdx.x * 4 + (threadIdx.x >> 6);  // t*B_ + b
    int lane = threadIdx.x & 63;
    bf16x8 h8 = *(const bf16x8*)(hall + (size_t)row * U_ + lane * 8);
    float p0 = 0, p1 = 0, p2 = 0;
#pragma unroll
    for (int k = 0; k < 8; k++) {
        float h = (float)h8[k];
        int u = lane * 8 + k;
        p0 += h * Wout[u * 3 + 0];
        p1 += h * Wout[u * 3 + 1];
        p2 += h * Wout[u * 3 + 2];
    }
    for (int off = 32; off; off >>= 1) {
        p0 += __shfl_down(p0, off, 64);
        p1 += __shfl_down(p1, off, 64);
        p2 += __shfl_down(p2, off, 64);
    }
    if (lane == 0) {
        int t = row >> 12, b = row & (B_ - 1);
        size_t o = ((size_t)b * T_ + t) * 3;
        out[o + 0] = p0 + bout[0];
        out[o + 1] = p1 + bout[1];
        out[o + 2] = p2 + bout[2];
    }
}

extern "C" void kernel_launch(void* const* d_in, const int* in_sizes, int n_in,
                              void* d_out, int out_size, void* d_ws, size_t ws_size,
                              hipStream_t stream) {
    const float* x   = (const float*)d_in[0];
    const float* W_r = (const float*)d_in[1];
    const float* b_r = (const float*)d_in[2];
    const float* W_q = (const float*)d_in[3];
    const float* b_q = (const float*)d_in[4];
    const float* W_s = (const float*)d_in[5];
    const float* b_s = (const float*)d_in[6];
    const float* W_o = (const float*)d_in[7];
    const float* b_o = (const float*)d_in[8];
    float* out = (float*)d_out;

    char* ws = (char*)d_ws;
    bf16_t* hhat  = (bf16_t*)ws; ws += (size_t)B_ * NRS * 2;           // 33.5 MB
    bf16_t* xtile = (bf16_t*)ws; ws += (size_t)T_ * XPT * 2;           // 33.5 MB
    bf16_t* hall  = (bf16_t*)ws; ws += (size_t)(T_ + 1) * B_ * U_ * 2; // 71 MB
    bf16_t* rh    = (bf16_t*)ws; ws += (size_t)B_ * U_ * 2;            // 4.2 MB
    bf16_t* WrsT  = (bf16_t*)ws; ws += (size_t)NC * K_ * 2;            // 12.6 MB
    bf16_t* Btile = (bf16_t*)ws; ws += (size_t)NC * K_ * 2;            // 12.6 MB
    bf16_t* htA   = (bf16_t*)ws; ws += (size_t)32 * HPH * 2;           // 4.2 MB
    bf16_t* htB   = (bf16_t*)ws; ws += (size_t)32 * HPH * 2;           // 4.2 MB
    bf16_t* Bq16  = (bf16_t*)ws; ws += (size_t)32 * QPP * 2;           // 0.79 MB
    float*  biasP = (float*)ws;  ws += (size_t)NC * 4;                 // 32 KB

    xtile_build<<<B_ * T_ * F_ / 8 / 256, 256, 0, stream>>>(x, xtile);
    transpose_perm<<<dim3(K_ / 32, NRS / 32), 256, 0, stream>>>(W_r, WrsT);
    transpose_perm<<<dim3(K_ / 32, NRS / 32), 256, 0, stream>>>(W_s, WrsT + (size_t)NRS * K_);
    btile_build<<<NC * 3, 256, 0, stream>>>(WrsT, Btile);
    bq16_build<<<K_ * U_ / 256, 256, 0, stream>>>(W_q, Bq16);
    bias_perm<<<NC / 256, 256, 0, stream>>>(b_r, b_s, biasP);

    // htile double buffer: read (t-1) from ht[t&1], write (t) to ht[(t+1)&1]
    bf16_t* htbuf[2] = {htA, htB};
    for (int t = 0; t < T_; t++) {
        const bf16_t* xt_t = xtile + (size_t)t * XPT;
        const bf16_t* htr  = htbuf[t & 1];
        bf16_t*       htw  = htbuf[(t + 1) & 1];
        bf16_t*       hn   = hall + (size_t)(t + 1) * B_ * U_;
        if (t == 0) {
            gemm_sq<1><<<dim3(32, 32), 256, 0, stream>>>(
                xt_t, htr, Btile, biasP, rh, Bq16, b_q, hhat, hn, htw);
        } else {
            gemm_r<<<dim3(32, 32), 256, 0, stream>>>(
                xt_t, htr, Btile, biasP, hhat, rh);
            gemm_sq<0><<<dim3(32, 32), 256, 0, stream>>>(
                xt_t, htr, Btile, biasP, rh, Bq16, b_q, hhat, hn, htw);
        }
    }
    out_all<<<B_ * T_ / 4, 256, 0, stream>>>(hall + (size_t)B_ * U_, W_o, b_o, out);
}

// Round 11
// 1519.749 us; speedup vs baseline: 1.0018x; 1.0018x over previous
//
#include <hip/hip_runtime.h>
#include <hip/hip_bf16.h>
#include <math.h>

#define B_   4096
#define T_   16
#define F_   256
#define U_   512
#define M_   8
#define K_   768    // F+U
#define NRS  4096   // U*M
#define NC   8192   // combined R|S output cols
#define LNT  1.1512925f  // 0.5*ln(10)

// chunk-major pre-tiled panel constants
#define XPH  32768   // x panel per (t,mh): 8 kt * 4096
#define XPT  1048576 // x per t: 32 mh * XPH
#define HPH  65536   // h panel per mh: 16 kt * 4096
#define BPH  98304   // B panel per NH: 24 kt * 4096
#define QPP  12288   // Bq16 panel per nh: 24 kt * 512

typedef __bf16 bf16_t;
typedef bf16_t bf16x8 __attribute__((ext_vector_type(8)));
typedef bf16_t bf16x4 __attribute__((ext_vector_type(4)));
typedef float  f32x4  __attribute__((ext_vector_type(4)));

__device__ inline void gl_lds16(const void* g, void* lds) {
    __builtin_amdgcn_global_load_lds(
        (const __attribute__((address_space(1))) unsigned int*)g,
        (__attribute__((address_space(3))) unsigned int*)lds, 16, 0, 0);
}

#define VMCNT(n) asm volatile("s_waitcnt vmcnt(" #n ")" ::: "memory")
#define LGKM0()  asm volatile("s_waitcnt lgkmcnt(0)" ::: "memory")
#define BAR()    __builtin_amdgcn_s_barrier()

// Chunk-major BK=32 slot: [4 ch][128 rows][8 bf16] = 8 KB; chunk c holds
// k=c*8..+7. A staging = 2 linear 16B loads/thread (256 thr).
__device__ inline void stage8(const bf16_t* src, bf16_t* dst, int tid) {
    gl_lds16(src + tid * 8,        (char*)dst + tid * 16);
    gl_lds16(src + tid * 8 + 2048, (char*)dst + tid * 16 + 4096);
}

// ---------------------------------------------------------------------------
// Shared K-loop structure (R11): A staged in LDS (shared by 2 waves), B
// FRAGMENT-DIRECT from L2 (chunk-major => contiguous 16B/lane; B working set
// 3MB/XCD under the swizzle -> L2-resident; removes ~60% of LDS-port traffic
// that R10's accounting identified as the K-loop floor). Counted vmcnt with
// derived N: per tile issue {stage A(t+1) [2 loads, OLDEST], b-prefetch(t+1)
// [4 VGPR loads]} -> VMCNT(4) drains exactly the A-stage, b stays in flight
// across the barrier (T4: never vmcnt(0) mid-loop). Register ping-pong b0/b1
// with compile-time parity (full unroll). Hazards: tile t writes Ahl[(t+1)&1]
// and reads Ahl[t&1] -- disjoint in every barrier window; stage visibility =
// VMCNT(4)+BAR before readers' window.
// ---------------------------------------------------------------------------
#define KLOOP_DEFS                                                             \
  f32x4 acc[4][4] = {};                                                        \
  bf16x8 b0[4], b1[4];

#define LDBG(D, T) do{ const bf16_t* _p = bp + (size_t)(T) * 4096 + bgo;       \
    D[0] = *(const bf16x8*)(_p);       D[1] = *(const bf16x8*)(_p + 128);      \
    D[2] = *(const bf16x8*)(_p + 256); D[3] = *(const bf16x8*)(_p + 384); }while(0)

#define KTILE(T, NT, BC, BN)                                                   \
  {                                                                            \
    const int p_ = (T) & 1, pn_ = p_ ^ 1;                                      \
    if ((T) < (NT) - 1) {                                                      \
      stage8(ASRC((T) + 1), &Ahl[pn_][0], tid);                                \
      LDBG(BN, (T) + 1);                                                       \
    }                                                                          \
    bf16x8 a_[4];                                                              \
    _Pragma("unroll") for (int i_ = 0; i_ < 4; ++i_)                           \
        a_[i_] = *(const bf16x8*)(&Ahl[p_][0] + aoff + i_ * 128);              \
    LGKM0();                                                                   \
    __builtin_amdgcn_s_setprio(1);                                             \
    _Pragma("unroll") for (int i_ = 0; i_ < 4; ++i_)                           \
      _Pragma("unroll") for (int j_ = 0; j_ < 4; ++j_)                         \
        acc[i_][j_] = __builtin_amdgcn_mfma_f32_16x16x32_bf16(                 \
            a_[i_], BC[j_], acc[i_][j_], 0, 0, 0);                             \
    __builtin_amdgcn_s_setprio(0);                                             \
    if ((T) < (NT) - 1) VMCNT(4);                                              \
    BAR();                                                                     \
  }

// ---------------------------------------------------------------------------
// R-half GEMM: 128x128 tile, 4 waves (2Mx2N), BK=32, 24 tiles, 16 KiB LDS.
// Epilogue: softmax + r*hhat reduce -> rh.
// ---------------------------------------------------------------------------
__global__ __launch_bounds__(256, 4) void gemm_r(
    const bf16_t* __restrict__ xt_t,   // [32 mh][8 kt][4][128][8]
    const bf16_t* __restrict__ ht,     // [32 mh][16 kt][4][128][8] (h(t-1))
    const bf16_t* __restrict__ Bt,     // [64 NH][24 kt][4][128][8]
    const float*  __restrict__ biasP,  // [NC] (perm)
    const bf16_t* __restrict__ hhat,   // [B_][NRS]
    bf16_t* __restrict__ rh)           // [B_][U_]
{
    __shared__ __attribute__((aligned(16))) bf16_t Ahl[2][4096];  // 16 KiB

    const int tid  = threadIdx.x;
    const int lane = tid & 63;
    const int wave = tid >> 6;

    const int lin = blockIdx.y * 32 + blockIdx.x;   // 1024 blocks
    const int c = lin & 7, q = lin >> 3;
    const int mh = (c >> 1) * 8 + (q & 7);
    const int nh = (c & 1) * 16 + (q >> 3);
    const int m0 = mh * 128;
    const int NH = nh;                              // R half

    const int wm = wave >> 1;
    const int wn = wave & 1;
    const int lr = lane & 15;
    const int kq = lane >> 4;

    const bf16_t* xp = xt_t + (size_t)mh * XPH;
    const bf16_t* hp = ht   + (size_t)mh * HPH;
    const bf16_t* bp = Bt   + (size_t)NH * BPH;

    const int aoff = kq * 1024 + (wm * 64 + lr) * 8;
    const int bgo  = kq * 1024 + (wn * 64 + lr) * 8;

    KLOOP_DEFS

#define ASRC(T) (((T) < 8) ? xp + (T) * 4096 : hp + ((T) - 8) * 4096)
    stage8(ASRC(0), &Ahl[0][0], tid);
    LDBG(b0, 0);
    VMCNT(4);           // drains the 2 stage loads (oldest); b0 stays in flight
    BAR();
#pragma unroll
    for (int tt = 0; tt < 24; tt += 2) {
        KTILE(tt, 24, b0, b1);
        KTILE(tt + 1, 24, b1, b0);
    }
#undef ASRC

    const int nb  = NH * 128 + wn * 64;
    const int u3  = lane & 7;
    const int m0v = ((lane >> 3) & 1) * 4;

    float bj4[4];
#pragma unroll
    for (int j = 0; j < 4; ++j) bj4[j] = biasP[nb + j * 16 + lr];

#pragma unroll
    for (int mi = 0; mi < 4; ++mi) {
        const int rowb = m0 + wm * 64 + mi * 16 + kq * 4;
#pragma unroll
        for (int r = 0; r < 4; ++r) {
            const int row = rowb + r;
            float e[4], sum = 0.f;
#pragma unroll
            for (int j = 0; j < 4; ++j) {
                float v = acc[mi][j][r] + bj4[j];
                float d = v - (float)(m0v + j) * LNT;
                e[j] = __expf(-d * d);
                sum += e[j];
            }
            sum += __shfl_xor(sum, 8, 64);
            const float inv = 1.0f / sum;
            bf16x4 h4 = *(const bf16x4*)(hhat + (size_t)row * NRS + nb + u3 * 8 + m0v);
            float rhv = 0.f;
#pragma unroll
            for (int j = 0; j < 4; ++j) rhv += e[j] * inv * (float)h4[j];
            rhv += __shfl_xor(rhv, 8, 64);
            if ((lane & 8) == 0)
                rh[(size_t)row * U_ + (nb >> 3) + u3] = (bf16_t)rhv;
        }
    }
}

// ---------------------------------------------------------------------------
// FUSED S-GEMM + q-GEMM + state update. Block = 128 rows x 128 S-cols,
// grid 1024, 4 waves, 24 KiB LDS -> 4 blk/CU.
// Phase 1: fragment-direct q-GEMM (proven R10: -19us vs staged) -> qls.
// Phase 2: S K-loop with B fragment-direct + counted vmcnt (this round).
// Phase 3: softmax + in-place hhat update; writes hall + htile(w).
// ---------------------------------------------------------------------------
template <int FIRST>
__global__ __launch_bounds__(256, 4) void gemm_sq(
    const bf16_t* __restrict__ xt_t,   // [32 mh][8 kt][4][128][8]
    const bf16_t* __restrict__ htr,    // h(t-1) tiles (read)
    const bf16_t* __restrict__ Bt,     // [64 NH][24 kt][4][128][8]
    const float*  __restrict__ biasP,  // [NC] (perm)
    const bf16_t* __restrict__ rh,     // [B_][U_]
    const bf16_t* __restrict__ Bq16,   // [32 nh][24 kt][4][16][8]
    const float*  __restrict__ bq,     // [U_]
    bf16_t* __restrict__ hhat,         // [B_][NRS] read(t-1)+write(t)
    bf16_t* __restrict__ hnext,        // hall slice t+1: [B_][U_]
    bf16_t* __restrict__ htw)          // h(t) tiles (write)
{
    __shared__ __attribute__((aligned(16))) bf16_t Ahl[2][4096];  // 16 KB
    __shared__ __attribute__((aligned(16))) float  qls[2048];     // 8 KB q[128][16]

    const int tid  = threadIdx.x;
    const int lane = tid & 63;
    const int wave = tid >> 6;

    const int lin = blockIdx.y * 32 + blockIdx.x;   // 1024 blocks
    const int c = lin & 7, qq = lin >> 3;
    const int mh = (c >> 1) * 8 + (qq & 7);
    const int nh = (c & 1) * 16 + (qq >> 3);
    const int m0 = mh * 128;
    const int NH = 32 + nh;                         // S half

    const int wm = wave >> 1;
    const int wn = wave & 1;
    const int lr = lane & 15;
    const int kq = lane >> 4;

    const bf16_t* xp = xt_t + (size_t)mh * XPH;
    const bf16_t* hp = htr  + (size_t)mh * HPH;
    const bf16_t* bp = Bt   + (size_t)NH * BPH;
    const bf16_t* bqp = Bq16 + (size_t)nh * QPP;

    // ---------------- Phase 1: q GEMM, fragment-direct (R10-proven) --------
    {
        f32x4 accq[2] = {};
        const bf16_t* bqk = bqp + kq * 128 + lr * 8;
        const bf16_t* xf  = xp + kq * 1024 + (wave * 32 + lr) * 8;
#pragma unroll
        for (int kt = 0; kt < 8; ++kt) {
            bf16x8 bqf = *(const bf16x8*)(bqk + kt * 512);
            bf16x8 a0  = *(const bf16x8*)(xf + kt * 4096);
            bf16x8 a1  = *(const bf16x8*)(xf + kt * 4096 + 128);
            accq[0] = __builtin_amdgcn_mfma_f32_16x16x32_bf16(a0, bqf, accq[0], 0, 0, 0);
            accq[1] = __builtin_amdgcn_mfma_f32_16x16x32_bf16(a1, bqf, accq[1], 0, 0, 0);
        }
        if (!FIRST) {
            const bf16_t* rf0 = rh + (size_t)(m0 + wave * 32 + lr) * U_ + kq * 8;
            const bf16_t* rf1 = rf0 + (size_t)16 * U_;
#pragma unroll
            for (int kt = 0; kt < 16; ++kt) {
                bf16x8 bqf = *(const bf16x8*)(bqk + (8 + kt) * 512);
                bf16x8 a0  = *(const bf16x8*)(rf0 + kt * 32);
                bf16x8 a1  = *(const bf16x8*)(rf1 + kt * 32);
                accq[0] = __builtin_amdgcn_mfma_f32_16x16x32_bf16(a0, bqf, accq[0], 0, 0, 0);
                accq[1] = __builtin_amdgcn_mfma_f32_16x16x32_bf16(a1, bqf, accq[1], 0, 0, 0);
            }
        }
        const float bqv = bq[nh * 16 + lr];
#pragma unroll
        for (int i = 0; i < 2; ++i)
#pragma unroll
            for (int r = 0; r < 4; ++r)
                qls[(wave * 32 + i * 16 + kq * 4 + r) * 16 + lr] =
                    tanhf(accq[i][r] + bqv);
    }
    BAR();

    // ---------------- Phase 2: S GEMM (B-direct + counted vmcnt) -----------
    const int aoff = kq * 1024 + (wm * 64 + lr) * 8;
    const int bgo  = kq * 1024 + (wn * 64 + lr) * 8;

    KLOOP_DEFS

#define ASRC(T) (((T) < 8) ? xp + (T) * 4096 : hp + ((T) - 8) * 4096)
    VMCNT(0);           // drain phase-1 stragglers so the counted scheme is exact
    stage8(ASRC(0), &Ahl[0][0], tid);
    LDBG(b0, 0);
    VMCNT(4);
    BAR();
    if (FIRST) {
#pragma unroll
        for (int tt = 0; tt < 8; tt += 2) {
            KTILE(tt, 8, b0, b1);
            KTILE(tt + 1, 8, b1, b0);
        }
    } else {
#pragma unroll
        for (int tt = 0; tt < 24; tt += 2) {
            KTILE(tt, 24, b0, b1);
            KTILE(tt + 1, 24, b1, b0);
        }
    }
#undef ASRC

    // ---------------- Phase 3: softmax + state update ----------------------
    const int nb  = NH * 128 + wn * 64;          // perm col base (S range)
    const int u3  = lane & 7;
    const int m0v = ((lane >> 3) & 1) * 4;
    const int hcol = nh * 128 + wn * 64;         // hhat col base

    const float DECL[4] = {0.0f, 0.9658531f, 0.9827783f, 0.9884856f};
    const float DECH[4] = {0.9913518f, 0.9930754f, 0.9942261f, 0.9950489f};

    float bj4[4];
#pragma unroll
    for (int j = 0; j < 4; ++j) bj4[j] = biasP[nb + j * 16 + lr];

#pragma unroll
    for (int mi = 0; mi < 4; ++mi) {
        const int rowb = m0 + wm * 64 + mi * 16 + kq * 4;
        const int rlb  = wm * 64 + mi * 16 + kq * 4;
#pragma unroll
        for (int r = 0; r < 4; ++r) {
            const int row = rowb + r;
            float e[4], sum = 0.f;
#pragma unroll
            for (int j = 0; j < 4; ++j) {
                float v = acc[mi][j][r] + bj4[j];
                float d = v - (float)(m0v + j) * LNT;
                e[j] = __expf(-d * d);
                sum += e[j];
            }
            sum += __shfl_xor(sum, 8, 64);
            const float inv = 1.0f / sum;
            const float qv = qls[(rlb + r) * 16 + wn * 8 + u3];

            const size_t ha = (size_t)row * NRS + hcol + u3 * 8 + m0v;
            bf16x4 h4;
            if (!FIRST) h4 = *(const bf16x4*)(hhat + ha);
            bf16x4 ho;
            float hs = 0.f;
#pragma unroll
            for (int j = 0; j < 4; ++j) {
                float s = e[j] * inv;
                float h = FIRST ? 0.f : (float)h4[j];
                float dec = m0v ? DECH[j] : DECL[j];
                float hn = ((1.f - s) * h + s * qv) * dec;
                ho[j] = (bf16_t)hn;
                hs += hn;
            }
            *(bf16x4*)(hhat + ha) = ho;
            hs += __shfl_xor(hs, 8, 64);
            if ((lane & 8) == 0) {
                const int u = nh * 16 + wn * 8 + u3;
                hnext[(size_t)row * U_ + u] = (bf16_t)hs;
                htw[((size_t)(row >> 7) * 16 + (u >> 5)) * 4096
                    + ((((u >> 3) & 3) * 128) + (row & 127)) * 8 + (u & 7)] = (bf16_t)hs;
            }
        }
    }
}

// dst[p][K_] = bf16(src[K_][NRS] col L), rows permuted within 64-groups.
__global__ void transpose_perm(const float* __restrict__ src, bf16_t* __restrict__ dst) {
    __shared__ float tl[32][33];
    int k0 = blockIdx.x * 32, n0 = blockIdx.y * 32;
    int tx = threadIdx.x & 31, ty = threadIdx.x >> 5;
#pragma unroll
    for (int i = 0; i < 32; i += 8)
        tl[ty + i][tx] = src[(size_t)(k0 + ty + i) * NRS + n0 + tx];
    __syncthreads();
#pragma unroll
    for (int i = 0; i < 32; i += 8) {
        int n = n0 + ty + i;
        int m = n & 7, u3v = (n >> 3) & 7;
        int p = (n & ~63) + (m & 3) * 16 + (m >> 2) * 8 + u3v;
        dst[(size_t)p * K_ + k0 + tx] = (bf16_t)tl[tx][ty + i];
    }
}

// BtN[NH][kt][4][128][8] (chunk-major) from WrsT [NC][K_] (perm rows).
__global__ void btile_build(const bf16_t* __restrict__ WrsT, bf16_t* __restrict__ Bt) {
    int n = blockIdx.x / 3;
    int k = (blockIdx.x % 3) * 256 + threadIdx.x;
    int NH = n >> 7, prow = n & 127;
    int kt = k >> 5, ch = (k >> 3) & 3, e = k & 7;
    Bt[(size_t)NH * BPH + (((size_t)kt * 4 + ch) * 128 + prow) * 8 + e]
        = WrsT[(size_t)n * K_ + k];
}

// Bq16[nh][kt][4 ch][16][8] from W_q f32 [K_][U_] (coalesced src read).
__global__ void bq16_build(const float* __restrict__ Wq, bf16_t* __restrict__ Bq16) {
    int i = blockIdx.x * 256 + threadIdx.x;   // K_*U_
    int k = i >> 9, u = i & 511;
    int nh = u >> 4, ul = u & 15;
    int kt = k >> 5, ch = (k >> 3) & 3, e = k & 7;
    Bq16[(size_t)nh * QPP + ((size_t)kt * 4 + ch) * 128 + ul * 8 + e] = (bf16_t)Wq[i];
}

__global__ void bias_perm(const float* __restrict__ b_r, const float* __restrict__ b_s,
                          float* __restrict__ biasP) {
    int p = blockIdx.x * 256 + threadIdx.x;  // NC
    int pr = p & 63, j = pr >> 4, lr = pr & 15;
    int L = (p & ~63) + (lr & 7) * 8 + ((lr >> 3) & 1) * 4 + j;
    biasP[p] = (L < NRS) ? b_r[L] : b_s[L - NRS];
}

// xtN[t][mh][kt][4][128][8] (chunk-major) from x f32 [B][T][F]. Vectorized:
// one thread = one 8-f chunk (2x float4 in, 1x bf16x8 out).
__global__ void xtile_build(const float* __restrict__ x, bf16_t* __restrict__ xt) {
    int idx = blockIdx.x * 256 + threadIdx.x;  // B_*T_*F_/8
    int b = idx >> 9;
    int rem = idx & 511;
    int t = rem >> 5, c8 = rem & 31;
    int f0 = c8 * 8;
    const float* src = x + ((size_t)b * T_ + t) * F_ + f0;
    float4 v0 = *(const float4*)(src);
    float4 v1 = *(const float4*)(src + 4);
    bf16x8 o;
    o[0] = (bf16_t)v0.x; o[1] = (bf16_t)v0.y; o[2] = (bf16_t)v0.z; o[3] = (bf16_t)v0.w;
    o[4] = (bf16_t)v1.x; o[5] = (bf16_t)v1.y; o[6] = (bf16_t)v1.z; o[7] = (bf16_t)v1.w;
    int mh = b >> 7, prow = b & 127;
    int kt = f0 >> 5, ch = (f0 >> 3) & 3;
    *(bf16x8*)(xt + (size_t)t * XPT + (size_t)mh * XPH
               + (((size_t)kt * 4 + ch) * 128 + prow) * 8) = o;
}

// One launch for all T steps: out[b,t,:] = hall[t][b][:] @ Wout + bout.
__global__ __launch_bounds__(256) void out_all(
    const bf16_t* __restrict__ hall,   // [T_][B_][U_] (slices 1..16 of alloc)
    const float* __restrict__ Wout,
    const float* __restrict__ bout,
    float* __restrict__ out)
{
    int row = blockIdx.x * 4 + (threadIdx.x >> 6);  // t*B_ + b
    int lane = threadIdx.x & 63;
    bf16x8 h8 = *(const bf16x8*)(hall + (size_t)row * U_ + lane * 8);
    float p0 = 0, p1 = 0, p2 = 0;
#pragma unroll
    for (int k = 0; k < 8; k++) {
        float h = (float)h8[k];
        int u = lane * 8 + k;
        p0 += h * Wout[u * 3 + 0];
        p1 += h * Wout[u * 3 + 1];
        p2 += h * Wout[u * 3 + 2];
    }
    for (int off = 32; off; off >>= 1) {
        p0 += __shfl_down(p0, off, 64);
        p1 += __shfl_down(p1, off, 64);
        p2 += __shfl_down(p2, off, 64);
    }
    if (lane == 0) {
        int t = row >> 12, b = row & (B_ - 1);
        size_t o = ((size_t)b * T_ + t) * 3;
        out[o + 0] = p0 + bout[0];
        out[o + 1] = p1 + bout[1];
        out[o + 2] = p2 + bout[2];
    }
}

extern "C" void kernel_launch(void* const* d_in, const int* in_sizes, int n_in,
                              void* d_out, int out_size, void* d_ws, size_t ws_size,
                              hipStream_t stream) {
    const float* x   = (const float*)d_in[0];
    const float* W_r = (const float*)d_in[1];
    const float* b_r = (const float*)d_in[2];
    const float* W_q = (const float*)d_in[3];
    const float* b_q = (const float*)d_in[4];
    const float* W_s = (const float*)d_in[5];
    const float* b_s = (const float*)d_in[6];
    const float* W_o = (const float*)d_in[7];
    const float* b_o = (const float*)d_in[8];
    float* out = (float*)d_out;

    char* ws = (char*)d_ws;
    bf16_t* hhat  = (bf16_t*)ws; ws += (size_t)B_ * NRS * 2;           // 33.5 MB
    bf16_t* xtile = (bf16_t*)ws; ws += (size_t)T_ * XPT * 2;           // 33.5 MB
    bf16_t* hall  = (bf16_t*)ws; ws += (size_t)(T_ + 1) * B_ * U_ * 2; // 71 MB
    bf16_t* rh    = (bf16_t*)ws; ws += (size_t)B_ * U_ * 2;            // 4.2 MB
    bf16_t* WrsT  = (bf16_t*)ws; ws += (size_t)NC * K_ * 2;            // 12.6 MB
    bf16_t* Btile = (bf16_t*)ws; ws += (size_t)NC * K_ * 2;            // 12.6 MB
    bf16_t* htA   = (bf16_t*)ws; ws += (size_t)32 * HPH * 2;           // 4.2 MB
    bf16_t* htB   = (bf16_t*)ws; ws += (size_t)32 * HPH * 2;           // 4.2 MB
    bf16_t* Bq16  = (bf16_t*)ws; ws += (size_t)32 * QPP * 2;           // 0.79 MB
    float*  biasP = (float*)ws;  ws += (size_t)NC * 4;                 // 32 KB

    xtile_build<<<B_ * T_ * F_ / 8 / 256, 256, 0, stream>>>(x, xtile);
    transpose_perm<<<dim3(K_ / 32, NRS / 32), 256, 0, stream>>>(W_r, WrsT);
    transpose_perm<<<dim3(K_ / 32, NRS / 32), 256, 0, stream>>>(W_s, WrsT + (size_t)NRS * K_);
    btile_build<<<NC * 3, 256, 0, stream>>>(WrsT, Btile);
    bq16_build<<<K_ * U_ / 256, 256, 0, stream>>>(W_q, Bq16);
    bias_perm<<<NC / 256, 256, 0, stream>>>(b_r, b_s, biasP);

    // htile double buffer: read (t-1) from ht[t&1], write (t) to ht[(t+1)&1]
    bf16_t* htbuf[2] = {htA, htB};
    for (int t = 0; t < T_; t++) {
        const bf16_t* xt_t = xtile + (size_t)t * XPT;
        const bf16_t* htr  = htbuf[t & 1];
        bf16_t*       htw  = htbuf[(t + 1) & 1];
        bf16_t*       hn   = hall + (size_t)(t + 1) * B_ * U_;
        if (t == 0) {
            gemm_sq<1><<<dim3(32, 32), 256, 0, stream>>>(
                xt_t, htr, Btile, biasP, rh, Bq16, b_q, hhat, hn, htw);
        } else {
            gemm_r<<<dim3(32, 32), 256, 0, stream>>>(
                xt_t, htr, Btile, biasP, hhat, rh);
            gemm_sq<0><<<dim3(32, 32), 256, 0, stream>>>(
                xt_t, htr, Btile, biasP, rh, Bq16, b_q, hhat, hn, htw);
        }
    }
    out_all<<<B_ * T_ / 4, 256, 0, stream>>>(hall + (size_t)B_ * U_, W_o, b_o, out);
}